// Round 2
// baseline (1032.640 us; speedup 1.0000x reference)
//
#include <hip/hip_runtime.h>
#include <hip/hip_bf16.h>

// Problem constants (match reference)
#define VV 50000
#define EE 100
#define HD 64
#define BB 128
#define TT 512
#define KK 12

// ---------- helpers ----------
__device__ __forceinline__ float bf_lo(unsigned u) { return __uint_as_float(u << 16); }
__device__ __forceinline__ float bf_hi(unsigned u) { return __uint_as_float(u & 0xffff0000u); }
__device__ __forceinline__ float rl_f(float v, int lane) {
    return __uint_as_float(__builtin_amdgcn_readlane(__float_as_uint(v), lane));
}
__device__ __forceinline__ float sigm_f(float x) { return 1.f / (1.f + __expf(-x)); }
__device__ __forceinline__ float tanh_f(float x) {
    float e = __expf(2.f * x);          // large x -> inf -> 1; very negative -> 0 -> -1
    return 1.f - 2.f / (e + 1.f);
}

// ---------- K1: vocab projection  proj[v][d*256 + j] = dot(emb[v], Wih_d[j]) ----------
__global__ __launch_bounds__(256) void k1_vocab_proj(
    const float* __restrict__ emb,
    const float* __restrict__ Wih_f, const float* __restrict__ Wih_b,
    __hip_bfloat16* __restrict__ proj, int vchunk)
{
    const int d  = blockIdx.x & 1;
    const int c  = blockIdx.x >> 1;
    const int j  = threadIdx.x;           // gate row 0..255
    const float* W = (d == 0 ? Wih_f : Wih_b) + (size_t)j * EE;

    float w[EE];
    #pragma unroll
    for (int k = 0; k < EE / 4; ++k) {
        float4 t = reinterpret_cast<const float4*>(W)[k];
        w[4*k+0] = t.x; w[4*k+1] = t.y; w[4*k+2] = t.z; w[4*k+3] = t.w;
    }

    int v0   = c * vchunk;
    int vend = min(v0 + vchunk, VV);
    for (int v = v0; v < vend; ++v) {
        const float4* er = reinterpret_cast<const float4*>(emb + (size_t)v * EE);
        float a0 = 0.f, a1 = 0.f, a2 = 0.f, a3 = 0.f;
        #pragma unroll
        for (int k = 0; k < EE / 4; ++k) {
            float4 e = er[k];
            a0 = fmaf(e.x, w[4*k+0], a0);
            a1 = fmaf(e.y, w[4*k+1], a1);
            a2 = fmaf(e.z, w[4*k+2], a2);
            a3 = fmaf(e.w, w[4*k+3], a3);
        }
        float acc = (a0 + a1) + (a2 + a3);
        proj[(size_t)v * 512 + d * 256 + j] = __float2bfloat16(acc);
    }
}

// ---------- K2: LSTM recurrence. One workgroup per (batch, dir). ----------
// 256 threads; thread tid owns gate row tid (wave w = gate type, lane u = hidden unit).
// All 4 waves redundantly keep (h_u, c_u) in lane u; h broadcast via v_readlane.
__global__ __launch_bounds__(256) void k2_lstm(
    const int* __restrict__ sent,
    const __hip_bfloat16* __restrict__ proj,
    const float* __restrict__ Whh_f, const float* __restrict__ Whh_b,
    const float* __restrict__ bih_f, const float* __restrict__ bhh_f,
    const float* __restrict__ bih_b, const float* __restrict__ bhh_b,
    const float* __restrict__ h0, const float* __restrict__ c0,
    __hip_bfloat16* __restrict__ Hbuf)
{
    const int b   = blockIdx.x >> 1;
    const int d   = blockIdx.x & 1;
    const int tid = threadIdx.x;
    const int u   = tid & 63;
    const int w   = tid >> 6;             // 0:i 1:f 2:g 3:o

    __shared__ float a_lds[256];

    const float* Whh = (d == 0 ? Whh_f : Whh_b) + (size_t)tid * HD;
    float wreg[HD];
    #pragma unroll
    for (int k = 0; k < HD / 4; ++k) {
        float4 t = reinterpret_cast<const float4*>(Whh)[k];
        wreg[4*k+0] = t.x; wreg[4*k+1] = t.y; wreg[4*k+2] = t.z; wreg[4*k+3] = t.w;
    }
    const float bias = (d == 0) ? (bih_f[tid] + bhh_f[tid]) : (bih_b[tid] + bhh_b[tid]);

    float h = h0[((size_t)d * BB + b) * HD + u];
    float c = c0[((size_t)d * BB + b) * HD + u];

    const int* srow = sent + (size_t)b * TT;
    // 2-deep xp prefetch
    int t0 = (d == 0) ? 0 : TT - 1;
    int t1 = (d == 0) ? 1 : TT - 2;
    float xp0 = __bfloat162float(proj[(size_t)srow[t0] * 512 + d * 256 + tid]);
    float xp1 = __bfloat162float(proj[(size_t)srow[t1] * 512 + d * 256 + tid]);

    for (int s = 0; s < TT; ++s) {
        const int t  = (d == 0) ? s : TT - 1 - s;
        const int sp = (s + 2 < TT) ? s + 2 : s;
        const int tp = (d == 0) ? sp : TT - 1 - sp;
        float xpn = __bfloat162float(proj[(size_t)srow[tp] * 512 + d * 256 + tid]);

        // g[tid] = bias + xp + sum_k h[k] * Whh[tid][k]
        float acc0 = bias + xp0, acc1 = 0.f, acc2 = 0.f, acc3 = 0.f;
        #pragma unroll
        for (int k = 0; k < HD; k += 4) {
            float hk0 = rl_f(h, k + 0);
            float hk1 = rl_f(h, k + 1);
            float hk2 = rl_f(h, k + 2);
            float hk3 = rl_f(h, k + 3);
            acc0 = fmaf(hk0, wreg[k + 0], acc0);
            acc1 = fmaf(hk1, wreg[k + 1], acc1);
            acc2 = fmaf(hk2, wreg[k + 2], acc2);
            acc3 = fmaf(hk3, wreg[k + 3], acc3);
        }
        float g = (acc0 + acc1) + (acc2 + acc3);

        float a = (w == 2) ? tanh_f(g) : sigm_f(g);   // wave-uniform branch
        a_lds[tid] = a;
        __syncthreads();
        float ai = a_lds[u];
        float af = a_lds[64 + u];
        float ag = a_lds[128 + u];
        float ao = a_lds[192 + u];
        c = af * c + ai * ag;
        h = ao * tanh_f(c);
        __syncthreads();   // protect a_lds before next iteration's writes

        if (tid < 64)
            Hbuf[((size_t)t * BB + b) * 128 + d * 64 + u] = __float2bfloat16(h);

        xp0 = xp1; xp1 = xpn;
    }
}

// ---------- K3: emissions  emis[b][t][k] = dot(Hcat[t][b][:128], W_out[k]) + b_out[k] ----------
__global__ __launch_bounds__(128) void k3_emis(
    const __hip_bfloat16* __restrict__ Hbuf,
    const float* __restrict__ W_out, const float* __restrict__ b_out,
    float* __restrict__ emis)
{
    const int t = blockIdx.x;
    const int b = threadIdx.x;
    __shared__ float Wl[KK * 128];
    for (int i = threadIdx.x; i < KK * 128; i += 128) Wl[i] = W_out[i];
    __syncthreads();

    const __hip_bfloat16* hrow = Hbuf + ((size_t)t * BB + b) * 128;
    float acc[KK];
    #pragma unroll
    for (int k = 0; k < KK; ++k) acc[k] = b_out[k];

    #pragma unroll
    for (int u0 = 0; u0 < 128; u0 += 8) {
        uint4 hv = *reinterpret_cast<const uint4*>(hrow + u0);
        float hf[8];
        hf[0] = bf_lo(hv.x); hf[1] = bf_hi(hv.x);
        hf[2] = bf_lo(hv.y); hf[3] = bf_hi(hv.y);
        hf[4] = bf_lo(hv.z); hf[5] = bf_hi(hv.z);
        hf[6] = bf_lo(hv.w); hf[7] = bf_hi(hv.w);
        #pragma unroll
        for (int k = 0; k < KK; ++k) {
            #pragma unroll
            for (int r = 0; r < 8; ++r)
                acc[k] = fmaf(hf[r], Wl[k * 128 + u0 + r], acc[k]);
        }
    }
    float* e = emis + ((size_t)b * TT + t) * KK;
    #pragma unroll
    for (int k = 0; k < KK; k += 4) {
        float4 v = make_float4(acc[k], acc[k+1], acc[k+2], acc[k+3]);
        *reinterpret_cast<float4*>(e + k) = v;
    }
}

// ---------- K4: Viterbi per batch (1 wave). ----------
__global__ __launch_bounds__(64) void k4_viterbi(
    const float* __restrict__ emis, const float* __restrict__ trans,
    float* __restrict__ out)
{
    const int b    = blockIdx.x;
    const int lane = threadIdx.x;
    __shared__ float em_lds[TT * KK];                 // 24 KB
    __shared__ unsigned char bp[(TT - 1) * KK + 4];   // ~6 KB

    // stage emissions for this batch into LDS
    {
        const uint4* e4 = reinterpret_cast<const uint4*>(emis + (size_t)b * TT * KK);
        uint4* l4 = reinterpret_cast<uint4*>(em_lds);
        for (int i = lane; i < TT * KK / 4; i += 64) l4[i] = e4[i];
    }
    __syncthreads();

    const int jj = (lane < KK) ? lane : 0;
    float tc[KK];
    #pragma unroll
    for (int i = 0; i < KK; ++i) tc[i] = trans[i * KK + jj];   // column jj

    float vj = em_lds[jj];            // t = 0 scores
    float sv[KK];
    #pragma unroll
    for (int i = 0; i < KK; ++i) sv[i] = rl_f(vj, i);

    for (int t = 1; t < TT; ++t) {
        float best = sv[0] + tc[0];
        int bi = 0;
        #pragma unroll
        for (int i = 1; i < KK; ++i) {
            float cnd = sv[i] + tc[i];
            bool gt = cnd > best;       // strict > keeps first max (matches jnp.argmax)
            best = gt ? cnd : best;
            bi   = gt ? i : bi;
        }
        if (lane < KK) bp[(t - 1) * KK + lane] = (unsigned char)bi;
        vj = best + em_lds[t * KK + jj];
        #pragma unroll
        for (int i = 0; i < KK; ++i) sv[i] = rl_f(vj, i);
    }

    // final max/argmax (sv uniform across lanes)
    float best = sv[0]; int bt = 0;
    #pragma unroll
    for (int i = 1; i < KK; ++i) { if (sv[i] > best) { best = sv[i]; bt = i; } }

    if (lane == 0) {
        out[b] = best;
        float* path = out + BB + (size_t)b * TT;
        int tag = bt;
        path[TT - 1] = (float)tag;
        for (int t = TT - 2; t >= 0; --t) {
            tag = bp[t * KK + tag];
            path[t] = (float)tag;
        }
    }
}

// ---------- launcher ----------
extern "C" void kernel_launch(void* const* d_in, const int* in_sizes, int n_in,
                              void* d_out, int out_size, void* d_ws, size_t ws_size,
                              hipStream_t stream) {
    const int*   sent  = (const int*)  d_in[0];
    const float* emb   = (const float*)d_in[1];
    const float* Wih_f = (const float*)d_in[2];
    const float* Whh_f = (const float*)d_in[3];
    const float* bih_f = (const float*)d_in[4];
    const float* bhh_f = (const float*)d_in[5];
    const float* Wih_b = (const float*)d_in[6];
    const float* Whh_b = (const float*)d_in[7];
    const float* bih_b = (const float*)d_in[8];
    const float* bhh_b = (const float*)d_in[9];
    const float* W_out = (const float*)d_in[10];
    const float* b_out = (const float*)d_in[11];
    const float* trans = (const float*)d_in[12];
    const float* h0    = (const float*)d_in[13];
    const float* c0    = (const float*)d_in[14];
    float* out = (float*)d_out;

    char* ws = (char*)d_ws;
    __hip_bfloat16* proj = (__hip_bfloat16*)ws;                       // V*512*2 B
    size_t off = (((size_t)VV * 512 * 2) + 255) & ~(size_t)255;
    __hip_bfloat16* Hbuf = (__hip_bfloat16*)(ws + off);               // T*B*128*2 B
    off += (((size_t)TT * BB * 128 * 2) + 255) & ~(size_t)255;
    float* emis = (float*)(ws + off);                                 // B*T*12*4 B

    const int vchunk = 128;
    dim3 g1(2 * ((VV + vchunk - 1) / vchunk));
    k1_vocab_proj<<<g1, 256, 0, stream>>>(emb, Wih_f, Wih_b, proj, vchunk);
    k2_lstm<<<dim3(2 * BB), 256, 0, stream>>>(sent, proj, Whh_f, Whh_b,
                                              bih_f, bhh_f, bih_b, bhh_b,
                                              h0, c0, Hbuf);
    k3_emis<<<dim3(TT), 128, 0, stream>>>(Hbuf, W_out, b_out, emis);
    k4_viterbi<<<dim3(BB), 64, 0, stream>>>(emis, trans, out);
}

// Round 3
// 638.996 us; speedup vs baseline: 1.6160x; 1.6160x over previous
//
#include <hip/hip_runtime.h>
#include <hip/hip_bf16.h>

// Problem constants (match reference)
#define VV 50000
#define EE 100
#define HD 64
#define BB 128
#define TT 512
#define KK 12

typedef unsigned int  uint32;
typedef unsigned short ushort16;
typedef __bf16 bf16x8 __attribute__((ext_vector_type(8)));
typedef float  f32x4  __attribute__((ext_vector_type(4)));

// ---------- helpers ----------
__device__ __forceinline__ float bf_lo(unsigned u) { return __uint_as_float(u << 16); }
__device__ __forceinline__ float bf_hi(unsigned u) { return __uint_as_float(u & 0xffff0000u); }
__device__ __forceinline__ float rl_f(float v, int lane) {
    return __uint_as_float(__builtin_amdgcn_readlane(__float_as_uint(v), lane));
}
__device__ __forceinline__ float sigm_f(float x) { return 1.f / (1.f + __expf(-x)); }
__device__ __forceinline__ float tanh_f(float x) {
    float e = __expf(2.f * x);
    return 1.f - 2.f / (e + 1.f);
}
__device__ __forceinline__ unsigned short f2bf(float v) {
    return __builtin_bit_cast(unsigned short, __float2bfloat16(v));
}

// ---------- K1: vocab projection as MFMA GEMM ----------
// proj[v][j] = dot(emb[v][0:100], Wcat[j][0:100]);  j = d*256 + gate_row
// Block tile: 64 (v) x 64 (j); K padded 100 -> 128; LDS stride 136 bf16 (+8 pad).
#define LDK 136

__global__ __launch_bounds__(256) void k1_mfma(
    const float* __restrict__ emb,
    const float* __restrict__ Wih_f, const float* __restrict__ Wih_b,
    __hip_bfloat16* __restrict__ proj)
{
    __shared__ unsigned short lA[64 * LDK];
    __shared__ unsigned short lB[64 * LDK];

    const int tid = threadIdx.x;
    const int v0  = blockIdx.x * 64;
    const int jb  = blockIdx.y;                         // 0..7
    const float* Wsrc = ((jb < 4) ? Wih_f : Wih_b) + (size_t)(jb & 3) * 64 * EE;

    // zero the pad region k in [96,136) (covers [100,128) actually used by MFMA)
    for (int i = tid; i < 64 * 20; i += 256) {
        int r = i / 20, c2 = i % 20;
        int off = r * LDK + 96 + c2 * 2;               // even -> 4B aligned
        *(uint32*)&lA[off] = 0u;
        *(uint32*)&lB[off] = 0u;
    }
    // load A tile (64 emb rows, contiguous f32), guard vocab tail
    {
        const float* asrc = emb + (size_t)v0 * EE;
        const int alim = (VV - v0 < 64 ? VV - v0 : 64) * EE;
        for (int i = tid; i < 64 * EE; i += 256) {
            float v = (i < alim) ? asrc[i] : 0.f;
            lA[(i / EE) * LDK + (i % EE)] = f2bf(v);
        }
    }
    // load B tile (64 W rows, contiguous f32)
    for (int i = tid; i < 64 * EE; i += 256) {
        lB[(i / EE) * LDK + (i % EE)] = f2bf(Wsrc[i]);
    }
    __syncthreads();

    const int w = tid >> 6, l = tid & 63;
    const int lo16 = l & 15, hi = l >> 4;

    f32x4 acc[4] = { {0.f,0.f,0.f,0.f}, {0.f,0.f,0.f,0.f},
                     {0.f,0.f,0.f,0.f}, {0.f,0.f,0.f,0.f} };
    #pragma unroll
    for (int s = 0; s < 4; ++s) {
        bf16x8 af = *(const bf16x8*)&lA[(w * 16 + lo16) * LDK + s * 32 + hi * 8];
        #pragma unroll
        for (int n = 0; n < 4; ++n) {
            bf16x8 bfr = *(const bf16x8*)&lB[(n * 16 + lo16) * LDK + s * 32 + hi * 8];
            acc[n] = __builtin_amdgcn_mfma_f32_16x16x32_bf16(af, bfr, acc[n], 0, 0, 0);
        }
    }
    // C/D layout (m89): col = lane&15, row = (lane>>4)*4 + reg
    #pragma unroll
    for (int n = 0; n < 4; ++n) {
        #pragma unroll
        for (int r = 0; r < 4; ++r) {
            int v = v0 + w * 16 + hi * 4 + r;
            int j = jb * 64 + n * 16 + lo16;
            if (v < VV)
                proj[(size_t)v * 512 + j] = __float2bfloat16(acc[n][r]);
        }
    }
}

// ---------- K2: LSTM recurrence. One workgroup per (batch, dir). ----------
// 256 threads; thread tid owns gate row tid. h broadcast via v_readlane.
// Double-buffered a_lds -> ONE barrier per step.
__global__ __launch_bounds__(256) void k2_lstm(
    const int* __restrict__ sent,
    const __hip_bfloat16* __restrict__ proj,
    const float* __restrict__ Whh_f, const float* __restrict__ Whh_b,
    const float* __restrict__ bih_f, const float* __restrict__ bhh_f,
    const float* __restrict__ bih_b, const float* __restrict__ bhh_b,
    const float* __restrict__ h0, const float* __restrict__ c0,
    __hip_bfloat16* __restrict__ Hbuf)
{
    const int b   = blockIdx.x >> 1;
    const int d   = blockIdx.x & 1;
    const int tid = threadIdx.x;
    const int u   = tid & 63;
    const int w   = tid >> 6;             // 0:i 1:f 2:g 3:o

    __shared__ float a_lds[2][256];

    const float* Whh = (d == 0 ? Whh_f : Whh_b) + (size_t)tid * HD;
    float wreg[HD];
    #pragma unroll
    for (int k = 0; k < HD / 4; ++k) {
        float4 t = reinterpret_cast<const float4*>(Whh)[k];
        wreg[4*k+0] = t.x; wreg[4*k+1] = t.y; wreg[4*k+2] = t.z; wreg[4*k+3] = t.w;
    }
    const float bias = (d == 0) ? (bih_f[tid] + bhh_f[tid]) : (bih_b[tid] + bhh_b[tid]);

    float h = h0[((size_t)d * BB + b) * HD + u];
    float c = c0[((size_t)d * BB + b) * HD + u];

    const int* srow = sent + (size_t)b * TT;
    int t0 = (d == 0) ? 0 : TT - 1;
    int t1 = (d == 0) ? 1 : TT - 2;
    float xp0 = __bfloat162float(proj[(size_t)srow[t0] * 512 + d * 256 + tid]);
    float xp1 = __bfloat162float(proj[(size_t)srow[t1] * 512 + d * 256 + tid]);

    int pb = 0;
    for (int s = 0; s < TT; ++s) {
        const int t  = (d == 0) ? s : TT - 1 - s;
        const int sp = (s + 2 < TT) ? s + 2 : s;
        const int tp = (d == 0) ? sp : TT - 1 - sp;
        float xpn = __bfloat162float(proj[(size_t)srow[tp] * 512 + d * 256 + tid]);

        float acc0 = bias + xp0, acc1 = 0.f, acc2 = 0.f, acc3 = 0.f;
        #pragma unroll
        for (int k = 0; k < HD; k += 4) {
            float hk0 = rl_f(h, k + 0);
            float hk1 = rl_f(h, k + 1);
            float hk2 = rl_f(h, k + 2);
            float hk3 = rl_f(h, k + 3);
            acc0 = fmaf(hk0, wreg[k + 0], acc0);
            acc1 = fmaf(hk1, wreg[k + 1], acc1);
            acc2 = fmaf(hk2, wreg[k + 2], acc2);
            acc3 = fmaf(hk3, wreg[k + 3], acc3);
        }
        float g = (acc0 + acc1) + (acc2 + acc3);

        float a = (w == 2) ? tanh_f(g) : sigm_f(g);   // wave-uniform branch
        a_lds[pb][tid] = a;
        __syncthreads();
        float ai = a_lds[pb][u];
        float af = a_lds[pb][64 + u];
        float ag = a_lds[pb][128 + u];
        float ao = a_lds[pb][192 + u];
        c = af * c + ai * ag;
        h = ao * tanh_f(c);
        pb ^= 1;                          // next step writes the other buffer

        if (tid < 64)
            Hbuf[((size_t)t * BB + b) * 128 + d * 64 + u] = __float2bfloat16(h);

        xp0 = xp1; xp1 = xpn;
    }
}

// ---------- K3: emissions ----------
__global__ __launch_bounds__(128) void k3_emis(
    const __hip_bfloat16* __restrict__ Hbuf,
    const float* __restrict__ W_out, const float* __restrict__ b_out,
    float* __restrict__ emis)
{
    const int t = blockIdx.x;
    const int b = threadIdx.x;
    __shared__ float Wl[KK * 128];
    for (int i = threadIdx.x; i < KK * 128; i += 128) Wl[i] = W_out[i];
    __syncthreads();

    const __hip_bfloat16* hrow = Hbuf + ((size_t)t * BB + b) * 128;
    float acc[KK];
    #pragma unroll
    for (int k = 0; k < KK; ++k) acc[k] = b_out[k];

    #pragma unroll
    for (int u0 = 0; u0 < 128; u0 += 8) {
        uint4 hv = *reinterpret_cast<const uint4*>(hrow + u0);
        float hf[8];
        hf[0] = bf_lo(hv.x); hf[1] = bf_hi(hv.x);
        hf[2] = bf_lo(hv.y); hf[3] = bf_hi(hv.y);
        hf[4] = bf_lo(hv.z); hf[5] = bf_hi(hv.z);
        hf[6] = bf_lo(hv.w); hf[7] = bf_hi(hv.w);
        #pragma unroll
        for (int k = 0; k < KK; ++k) {
            #pragma unroll
            for (int r = 0; r < 8; ++r)
                acc[k] = fmaf(hf[r], Wl[k * 128 + u0 + r], acc[k]);
        }
    }
    float* e = emis + ((size_t)b * TT + t) * KK;
    #pragma unroll
    for (int k = 0; k < KK; k += 4) {
        float4 v = make_float4(acc[k], acc[k+1], acc[k+2], acc[k+3]);
        *reinterpret_cast<float4*>(e + k) = v;
    }
}

// ---------- K4: Viterbi per batch (1 wave). ----------
__global__ __launch_bounds__(64) void k4_viterbi(
    const float* __restrict__ emis, const float* __restrict__ trans,
    float* __restrict__ out)
{
    const int b    = blockIdx.x;
    const int lane = threadIdx.x;
    __shared__ float em_lds[TT * KK];                 // 24 KB
    __shared__ unsigned char bp[(TT - 1) * KK + 4];

    {
        const uint4* e4 = reinterpret_cast<const uint4*>(emis + (size_t)b * TT * KK);
        uint4* l4 = reinterpret_cast<uint4*>(em_lds);
        for (int i = lane; i < TT * KK / 4; i += 64) l4[i] = e4[i];
    }
    __syncthreads();

    const int jj = (lane < KK) ? lane : 0;
    float tc[KK];
    #pragma unroll
    for (int i = 0; i < KK; ++i) tc[i] = trans[i * KK + jj];   // column jj

    float vj = em_lds[jj];
    float sv[KK];
    #pragma unroll
    for (int i = 0; i < KK; ++i) sv[i] = rl_f(vj, i);

    for (int t = 1; t < TT; ++t) {
        float best = sv[0] + tc[0];
        int bi = 0;
        #pragma unroll
        for (int i = 1; i < KK; ++i) {
            float cnd = sv[i] + tc[i];
            bool gt = cnd > best;       // strict > keeps first max (jnp.argmax)
            best = gt ? cnd : best;
            bi   = gt ? i : bi;
        }
        if (lane < KK) bp[(t - 1) * KK + lane] = (unsigned char)bi;
        vj = best + em_lds[t * KK + jj];
        #pragma unroll
        for (int i = 0; i < KK; ++i) sv[i] = rl_f(vj, i);
    }

    float best = sv[0]; int bt = 0;
    #pragma unroll
    for (int i = 1; i < KK; ++i) { if (sv[i] > best) { best = sv[i]; bt = i; } }

    if (lane == 0) {
        out[b] = best;
        float* path = out + BB + (size_t)b * TT;
        int tag = bt;
        path[TT - 1] = (float)tag;
        for (int t = TT - 2; t >= 0; --t) {
            tag = bp[t * KK + tag];
            path[t] = (float)tag;
        }
    }
}

// ---------- launcher ----------
extern "C" void kernel_launch(void* const* d_in, const int* in_sizes, int n_in,
                              void* d_out, int out_size, void* d_ws, size_t ws_size,
                              hipStream_t stream) {
    const int*   sent  = (const int*)  d_in[0];
    const float* emb   = (const float*)d_in[1];
    const float* Wih_f = (const float*)d_in[2];
    const float* Whh_f = (const float*)d_in[3];
    const float* bih_f = (const float*)d_in[4];
    const float* bhh_f = (const float*)d_in[5];
    const float* Wih_b = (const float*)d_in[6];
    const float* Whh_b = (const float*)d_in[7];
    const float* bih_b = (const float*)d_in[8];
    const float* bhh_b = (const float*)d_in[9];
    const float* W_out = (const float*)d_in[10];
    const float* b_out = (const float*)d_in[11];
    const float* trans = (const float*)d_in[12];
    const float* h0    = (const float*)d_in[13];
    const float* c0    = (const float*)d_in[14];
    float* out = (float*)d_out;

    char* ws = (char*)d_ws;
    __hip_bfloat16* proj = (__hip_bfloat16*)ws;                       // V*512*2 B
    size_t off = (((size_t)VV * 512 * 2) + 255) & ~(size_t)255;
    __hip_bfloat16* Hbuf = (__hip_bfloat16*)(ws + off);               // T*B*128*2 B
    off += (((size_t)TT * BB * 128 * 2) + 255) & ~(size_t)255;
    float* emis = (float*)(ws + off);                                 // B*T*12*4 B

    dim3 g1((VV + 63) / 64, 8);
    k1_mfma<<<g1, 256, 0, stream>>>(emb, Wih_f, Wih_b, proj);
    k2_lstm<<<dim3(2 * BB), 256, 0, stream>>>(sent, proj, Whh_f, Whh_b,
                                              bih_f, bhh_f, bih_b, bhh_b,
                                              h0, c0, Hbuf);
    k3_emis<<<dim3(TT), 128, 0, stream>>>(Hbuf, W_out, b_out, emis);
    k4_viterbi<<<dim3(BB), 64, 0, stream>>>(emis, trans, out);
}

// Round 4
// 594.526 us; speedup vs baseline: 1.7369x; 1.0748x over previous
//
#include <hip/hip_runtime.h>
#include <hip/hip_bf16.h>

// Problem constants (match reference)
#define VV 50000
#define EE 100
#define HD 64
#define BB 128
#define TT 512
#define KK 12

typedef unsigned int uint32;
typedef __bf16 bf16x8 __attribute__((ext_vector_type(8)));
typedef float  f32x4  __attribute__((ext_vector_type(4)));

// ---------- helpers ----------
__device__ __forceinline__ float bf_lo(unsigned u) { return __uint_as_float(u << 16); }
__device__ __forceinline__ float bf_hi(unsigned u) { return __uint_as_float(u & 0xffff0000u); }
__device__ __forceinline__ float rl_f(float v, int lane) {
    return __uint_as_float(__builtin_amdgcn_readlane(__float_as_uint(v), lane));
}
__device__ __forceinline__ float sigm_f(float x) { return 1.f / (1.f + __expf(-x)); }
__device__ __forceinline__ float tanh_f(float x) {
    float e = __expf(2.f * x);
    return 1.f - 2.f / (e + 1.f);
}
__device__ __forceinline__ unsigned short f2bf(float v) {
    return __builtin_bit_cast(unsigned short, __float2bfloat16(v));
}
// Barrier that does NOT drain vmcnt: LDS-visibility only (keeps prefetch loads
// and Hbuf stores in flight across the barrier — the round-3 1.2k-cy stall).
__device__ __forceinline__ void lds_barrier() {
    asm volatile("s_waitcnt lgkmcnt(0)" ::: "memory");
    __builtin_amdgcn_s_barrier();
    asm volatile("" ::: "memory");
}

// ---------- K1: vocab projection as MFMA GEMM, all 8 j-tiles per block ----------
// proj[v][j] = dot(emb[v][0:100], Wcat[j][0:100]);  j = d*256 + gate_row
#define LDK 136

__global__ __launch_bounds__(256) void k1_mfma(
    const float* __restrict__ emb,
    const float* __restrict__ Wih_f, const float* __restrict__ Wih_b,
    __hip_bfloat16* __restrict__ proj)
{
    __shared__ unsigned short lA[64 * LDK];
    __shared__ unsigned short lB[64 * LDK];

    const int tid = threadIdx.x;
    const int v0  = blockIdx.x * 64;

    // zero pad cols [96,136) of both tiles (k in [100,128) must be 0 for MFMA)
    for (int i = tid; i < 64 * 20; i += 256) {
        int r = i / 20, c2 = i % 20;
        *(uint32*)&lA[r * LDK + 96 + c2 * 2] = 0u;
        *(uint32*)&lB[r * LDK + 96 + c2 * 2] = 0u;
    }
    // stage A tile (64 emb rows), guard vocab tail
    {
        const float* asrc = emb + (size_t)v0 * EE;
        const int alim = (VV - v0 < 64 ? VV - v0 : 64) * EE;
        for (int i = tid; i < 64 * EE; i += 256) {
            float v = (i < alim) ? asrc[i] : 0.f;
            lA[(i / EE) * LDK + (i % EE)] = f2bf(v);
        }
    }
    __syncthreads();

    const int w = tid >> 6, l = tid & 63;
    const int lo16 = l & 15, hi = l >> 4;

    // A fragments cached in registers across all 8 jb iterations
    bf16x8 afr[4];
    #pragma unroll
    for (int s = 0; s < 4; ++s)
        afr[s] = *(const bf16x8*)&lA[(w * 16 + lo16) * LDK + s * 32 + hi * 8];

    for (int jb = 0; jb < 8; ++jb) {
        const float* Wsrc = ((jb < 4) ? Wih_f : Wih_b) + (size_t)(jb & 3) * 64 * EE;
        __syncthreads();                       // previous iter's MFMA reads done
        for (int i = tid; i < 64 * EE; i += 256)
            lB[(i / EE) * LDK + (i % EE)] = f2bf(Wsrc[i]);
        __syncthreads();

        f32x4 acc[4] = { {0.f,0.f,0.f,0.f}, {0.f,0.f,0.f,0.f},
                         {0.f,0.f,0.f,0.f}, {0.f,0.f,0.f,0.f} };
        #pragma unroll
        for (int s = 0; s < 4; ++s) {
            #pragma unroll
            for (int n = 0; n < 4; ++n) {
                bf16x8 bfr = *(const bf16x8*)&lB[(n * 16 + lo16) * LDK + s * 32 + hi * 8];
                acc[n] = __builtin_amdgcn_mfma_f32_16x16x32_bf16(afr[s], bfr, acc[n], 0, 0, 0);
            }
        }
        // C/D layout (m89): col = lane&15, row = (lane>>4)*4 + reg
        #pragma unroll
        for (int n = 0; n < 4; ++n) {
            #pragma unroll
            for (int r = 0; r < 4; ++r) {
                int v = v0 + w * 16 + hi * 4 + r;
                int j = jb * 64 + n * 16 + lo16;
                if (v < VV)
                    proj[(size_t)v * 512 + j] = __float2bfloat16(acc[n][r]);
            }
        }
    }
}

// ---------- K2: LSTM recurrence. One workgroup per (batch, dir). ----------
// 256 threads; thread tid owns gate row tid (wave w = gate, lane u = unit).
// h broadcast via v_readlane; activations exchanged via double-buffered LDS
// with a vmcnt-preserving barrier (one per step).
__global__ __launch_bounds__(256) void k2_lstm(
    const int* __restrict__ sent,
    const __hip_bfloat16* __restrict__ proj,
    const float* __restrict__ Whh_f, const float* __restrict__ Whh_b,
    const float* __restrict__ bih_f, const float* __restrict__ bhh_f,
    const float* __restrict__ bih_b, const float* __restrict__ bhh_b,
    const float* __restrict__ h0, const float* __restrict__ c0,
    __hip_bfloat16* __restrict__ Hbuf)
{
    const int b   = blockIdx.x >> 1;
    const int d   = blockIdx.x & 1;
    const int tid = threadIdx.x;
    const int u   = tid & 63;
    const int w   = tid >> 6;             // 0:i 1:f 2:g 3:o

    __shared__ float a_lds[2][256];

    const float* Whh = (d == 0 ? Whh_f : Whh_b) + (size_t)tid * HD;
    float wreg[HD];
    #pragma unroll
    for (int k = 0; k < HD / 4; ++k) {
        float4 t = reinterpret_cast<const float4*>(Whh)[k];
        wreg[4*k+0] = t.x; wreg[4*k+1] = t.y; wreg[4*k+2] = t.z; wreg[4*k+3] = t.w;
    }
    const float bias = (d == 0) ? (bih_f[tid] + bhh_f[tid]) : (bih_b[tid] + bhh_b[tid]);

    float h = h0[((size_t)d * BB + b) * HD + u];
    float c = c0[((size_t)d * BB + b) * HD + u];

    const int* srow = sent + (size_t)b * TT;
    const int tstep = (d == 0) ? 1 : -1;
    const int t0    = (d == 0) ? 0 : TT - 1;

    // xp pipeline: xp0 for step s, xp1 for s+1 in flight; idx2 = vocab index for
    // the gather issued at step s (covers s+2), loaded one step early.
    float xp0 = __bfloat162float(proj[(size_t)srow[t0] * 512 + d * 256 + tid]);
    float xp1 = __bfloat162float(proj[(size_t)srow[t0 + tstep] * 512 + d * 256 + tid]);
    int  idx2 = srow[t0 + 2 * tstep];

    // incremental Hbuf pointer (wave 0 stores)
    __hip_bfloat16* hp = Hbuf + ((size_t)t0 * BB + b) * 128 + d * 64 + u;
    const ptrdiff_t hstride = (ptrdiff_t)tstep * BB * 128;

    int pb = 0;
    for (int s = 0; s < TT; ++s) {
        // issue gather for step s+2 (address ready in registers)
        float xpn = __bfloat162float(proj[(size_t)idx2 * 512 + d * 256 + tid]);
        // load vocab index for step s+3 (consumed next iteration)
        int s3 = (s + 3 < TT) ? s + 3 : TT - 1;
        idx2 = srow[t0 + s3 * tstep];

        // g[tid] = bias + xp + sum_k h[k] * Whh[tid][k]
        float acc0 = bias + xp0, acc1 = 0.f, acc2 = 0.f, acc3 = 0.f;
        #pragma unroll
        for (int k = 0; k < HD; k += 4) {
            float hk0 = rl_f(h, k + 0);
            float hk1 = rl_f(h, k + 1);
            float hk2 = rl_f(h, k + 2);
            float hk3 = rl_f(h, k + 3);
            acc0 = fmaf(hk0, wreg[k + 0], acc0);
            acc1 = fmaf(hk1, wreg[k + 1], acc1);
            acc2 = fmaf(hk2, wreg[k + 2], acc2);
            acc3 = fmaf(hk3, wreg[k + 3], acc3);
        }
        float g = (acc0 + acc1) + (acc2 + acc3);

        float a = (w == 2) ? tanh_f(g) : sigm_f(g);   // wave-uniform branch
        a_lds[pb][tid] = a;
        lds_barrier();                                // lgkmcnt only, vmcnt stays in flight
        float ai = a_lds[pb][u];
        float af = a_lds[pb][64 + u];
        float ag = a_lds[pb][128 + u];
        float ao = a_lds[pb][192 + u];
        c = af * c + ai * ag;
        h = ao * tanh_f(c);
        pb ^= 1;

        if (tid < 64) {
            *hp = __float2bfloat16(h);
            hp += hstride;
        }
        xp0 = xp1; xp1 = xpn;
    }
}

// ---------- K3: emissions ----------
__global__ __launch_bounds__(128) void k3_emis(
    const __hip_bfloat16* __restrict__ Hbuf,
    const float* __restrict__ W_out, const float* __restrict__ b_out,
    float* __restrict__ emis)
{
    const int t = blockIdx.x;
    const int b = threadIdx.x;
    __shared__ float Wl[KK * 128];
    for (int i = threadIdx.x; i < KK * 128; i += 128) Wl[i] = W_out[i];
    __syncthreads();

    const __hip_bfloat16* hrow = Hbuf + ((size_t)t * BB + b) * 128;
    float acc[KK];
    #pragma unroll
    for (int k = 0; k < KK; ++k) acc[k] = b_out[k];

    #pragma unroll
    for (int u0 = 0; u0 < 128; u0 += 8) {
        uint4 hv = *reinterpret_cast<const uint4*>(hrow + u0);
        float hf[8];
        hf[0] = bf_lo(hv.x); hf[1] = bf_hi(hv.x);
        hf[2] = bf_lo(hv.y); hf[3] = bf_hi(hv.y);
        hf[4] = bf_lo(hv.z); hf[5] = bf_hi(hv.z);
        hf[6] = bf_lo(hv.w); hf[7] = bf_hi(hv.w);
        #pragma unroll
        for (int k = 0; k < KK; ++k) {
            #pragma unroll
            for (int r = 0; r < 8; ++r)
                acc[k] = fmaf(hf[r], Wl[k * 128 + u0 + r], acc[k]);
        }
    }
    float* e = emis + ((size_t)b * TT + t) * KK;
    #pragma unroll
    for (int k = 0; k < KK; k += 4) {
        float4 v = make_float4(acc[k], acc[k+1], acc[k+2], acc[k+3]);
        *reinterpret_cast<float4*>(e + k) = v;
    }
}

// ---------- K4: Viterbi per batch (1 wave). ----------
__global__ __launch_bounds__(64) void k4_viterbi(
    const float* __restrict__ emis, const float* __restrict__ trans,
    float* __restrict__ out)
{
    const int b    = blockIdx.x;
    const int lane = threadIdx.x;
    __shared__ float em_lds[TT * KK];                 // 24 KB
    __shared__ unsigned char bp[(TT - 1) * KK + 4];

    {
        const uint4* e4 = reinterpret_cast<const uint4*>(emis + (size_t)b * TT * KK);
        uint4* l4 = reinterpret_cast<uint4*>(em_lds);
        for (int i = lane; i < TT * KK / 4; i += 64) l4[i] = e4[i];
    }
    __syncthreads();

    const int jj = (lane < KK) ? lane : 0;
    float tc[KK];
    #pragma unroll
    for (int i = 0; i < KK; ++i) tc[i] = trans[i * KK + jj];   // column jj

    float vj = em_lds[jj];
    float sv[KK];
    #pragma unroll
    for (int i = 0; i < KK; ++i) sv[i] = rl_f(vj, i);

    for (int t = 1; t < TT; ++t) {
        float best = sv[0] + tc[0];
        int bi = 0;
        #pragma unroll
        for (int i = 1; i < KK; ++i) {
            float cnd = sv[i] + tc[i];
            bool gt = cnd > best;       // strict > keeps first max (jnp.argmax)
            best = gt ? cnd : best;
            bi   = gt ? i : bi;
        }
        if (lane < KK) bp[(t - 1) * KK + lane] = (unsigned char)bi;
        vj = best + em_lds[t * KK + jj];
        #pragma unroll
        for (int i = 0; i < KK; ++i) sv[i] = rl_f(vj, i);
    }

    float best = sv[0]; int bt = 0;
    #pragma unroll
    for (int i = 1; i < KK; ++i) { if (sv[i] > best) { best = sv[i]; bt = i; } }

    if (lane == 0) {
        out[b] = best;
        float* path = out + BB + (size_t)b * TT;
        int tag = bt;
        path[TT - 1] = (float)tag;
        for (int t = TT - 2; t >= 0; --t) {
            tag = bp[t * KK + tag];
            path[t] = (float)tag;
        }
    }
}

// ---------- launcher ----------
extern "C" void kernel_launch(void* const* d_in, const int* in_sizes, int n_in,
                              void* d_out, int out_size, void* d_ws, size_t ws_size,
                              hipStream_t stream) {
    const int*   sent  = (const int*)  d_in[0];
    const float* emb   = (const float*)d_in[1];
    const float* Wih_f = (const float*)d_in[2];
    const float* Whh_f = (const float*)d_in[3];
    const float* bih_f = (const float*)d_in[4];
    const float* bhh_f = (const float*)d_in[5];
    const float* Wih_b = (const float*)d_in[6];
    const float* Whh_b = (const float*)d_in[7];
    const float* bih_b = (const float*)d_in[8];
    const float* bhh_b = (const float*)d_in[9];
    const float* W_out = (const float*)d_in[10];
    const float* b_out = (const float*)d_in[11];
    const float* trans = (const float*)d_in[12];
    const float* h0    = (const float*)d_in[13];
    const float* c0    = (const float*)d_in[14];
    float* out = (float*)d_out;

    char* ws = (char*)d_ws;
    __hip_bfloat16* proj = (__hip_bfloat16*)ws;                       // V*512*2 B
    size_t off = (((size_t)VV * 512 * 2) + 255) & ~(size_t)255;
    __hip_bfloat16* Hbuf = (__hip_bfloat16*)(ws + off);               // T*B*128*2 B
    off += (((size_t)TT * BB * 128 * 2) + 255) & ~(size_t)255;
    float* emis = (float*)(ws + off);                                 // B*T*12*4 B

    k1_mfma<<<dim3((VV + 63) / 64), 256, 0, stream>>>(emb, Wih_f, Wih_b, proj);
    k2_lstm<<<dim3(2 * BB), 256, 0, stream>>>(sent, proj, Whh_f, Whh_b,
                                              bih_f, bhh_f, bih_b, bhh_b,
                                              h0, c0, Hbuf);
    k3_emis<<<dim3(TT), 128, 0, stream>>>(Hbuf, W_out, b_out, emis);
    k4_viterbi<<<dim3(BB), 64, 0, stream>>>(emis, trans, out);
}

// Round 5
// 540.313 us; speedup vs baseline: 1.9112x; 1.1003x over previous
//
#include <hip/hip_runtime.h>
#include <hip/hip_bf16.h>

// Problem constants (match reference)
#define VV 50000
#define EE 100
#define HD 64
#define BB 128
#define TT 512
#define KK 12

typedef unsigned int uint32;
typedef __bf16 bf16x8 __attribute__((ext_vector_type(8)));
typedef float  f32x4  __attribute__((ext_vector_type(4)));

// ---------- helpers ----------
__device__ __forceinline__ float bf_lo(unsigned u) { return __uint_as_float(u << 16); }
__device__ __forceinline__ float bf_hi(unsigned u) { return __uint_as_float(u & 0xffff0000u); }
__device__ __forceinline__ float rl_f(float v, int lane) {
    return __uint_as_float(__builtin_amdgcn_readlane(__float_as_uint(v), lane));
}
__device__ __forceinline__ float sigm_f(float x) { return 1.f / (1.f + __expf(-x)); }
__device__ __forceinline__ float tanh_f(float x) {
    float e = __expf(2.f * x);
    return 1.f - 2.f / (e + 1.f);
}
__device__ __forceinline__ unsigned short f2bf(float v) {
    return __builtin_bit_cast(unsigned short, __float2bfloat16(v));
}
// Barrier that does NOT drain vmcnt (LDS visibility only).
__device__ __forceinline__ void lds_barrier() {
    asm volatile("s_waitcnt lgkmcnt(0)" ::: "memory");
    __builtin_amdgcn_s_barrier();
    asm volatile("" ::: "memory");
}

// ---------- K1: vocab projection as MFMA GEMM, all 8 j-tiles per block ----------
#define LDK 136

__global__ __launch_bounds__(256) void k1_mfma(
    const float* __restrict__ emb,
    const float* __restrict__ Wih_f, const float* __restrict__ Wih_b,
    __hip_bfloat16* __restrict__ proj)
{
    __shared__ unsigned short lA[64 * LDK];
    __shared__ unsigned short lB[64 * LDK];

    const int tid = threadIdx.x;
    const int v0  = blockIdx.x * 64;

    for (int i = tid; i < 64 * 20; i += 256) {
        int r = i / 20, c2 = i % 20;
        *(uint32*)&lA[r * LDK + 96 + c2 * 2] = 0u;
        *(uint32*)&lB[r * LDK + 96 + c2 * 2] = 0u;
    }
    {
        const float* asrc = emb + (size_t)v0 * EE;
        const int alim = (VV - v0 < 64 ? VV - v0 : 64) * EE;
        for (int i = tid; i < 64 * EE; i += 256) {
            float v = (i < alim) ? asrc[i] : 0.f;
            lA[(i / EE) * LDK + (i % EE)] = f2bf(v);
        }
    }
    __syncthreads();

    const int w = tid >> 6, l = tid & 63;
    const int lo16 = l & 15, hi = l >> 4;

    bf16x8 afr[4];
    #pragma unroll
    for (int s = 0; s < 4; ++s)
        afr[s] = *(const bf16x8*)&lA[(w * 16 + lo16) * LDK + s * 32 + hi * 8];

    for (int jb = 0; jb < 8; ++jb) {
        const float* Wsrc = ((jb < 4) ? Wih_f : Wih_b) + (size_t)(jb & 3) * 64 * EE;
        __syncthreads();
        for (int i = tid; i < 64 * EE; i += 256)
            lB[(i / EE) * LDK + (i % EE)] = f2bf(Wsrc[i]);
        __syncthreads();

        f32x4 acc[4] = { {0.f,0.f,0.f,0.f}, {0.f,0.f,0.f,0.f},
                         {0.f,0.f,0.f,0.f}, {0.f,0.f,0.f,0.f} };
        #pragma unroll
        for (int s = 0; s < 4; ++s) {
            #pragma unroll
            for (int n = 0; n < 4; ++n) {
                bf16x8 bfr = *(const bf16x8*)&lB[(n * 16 + lo16) * LDK + s * 32 + hi * 8];
                acc[n] = __builtin_amdgcn_mfma_f32_16x16x32_bf16(afr[s], bfr, acc[n], 0, 0, 0);
            }
        }
        #pragma unroll
        for (int n = 0; n < 4; ++n) {
            #pragma unroll
            for (int r = 0; r < 4; ++r) {
                int v = v0 + w * 16 + hi * 4 + r;
                int j = jb * 64 + n * 16 + lo16;
                if (v < VV)
                    proj[(size_t)v * 512 + j] = __float2bfloat16(acc[n][r]);
            }
        }
    }
}

// ---------- K2: LSTM recurrence. One workgroup per (batch, dir). ----------
// 256 threads; thread tid owns gate row tid (wave w = gate, lane u = unit).
// __launch_bounds__(256,2): cap VGPR budget at 128 so wreg[64] stays in arch
// VGPRs (round-4: default budget AGPR-ized it, VGPR_Count=44) and 2 blocks/CU
// can co-reside. xp gathers burst-prefetched 8 steps ahead (round-4: per-step
// serialized gather latency).
__global__ __launch_bounds__(256, 2) void k2_lstm(
    const int* __restrict__ sent,
    const __hip_bfloat16* __restrict__ proj,
    const float* __restrict__ Whh_f, const float* __restrict__ Whh_b,
    const float* __restrict__ bih_f, const float* __restrict__ bhh_f,
    const float* __restrict__ bih_b, const float* __restrict__ bhh_b,
    const float* __restrict__ h0, const float* __restrict__ c0,
    __hip_bfloat16* __restrict__ Hbuf)
{
    const int b   = blockIdx.x >> 1;
    const int d   = blockIdx.x & 1;
    const int tid = threadIdx.x;
    const int u   = tid & 63;
    const int w   = tid >> 6;             // 0:i 1:f 2:g 3:o

    __shared__ float a_lds[2][256];

    const float* Whh = (d == 0 ? Whh_f : Whh_b) + (size_t)tid * HD;
    float wreg[HD];
    #pragma unroll
    for (int k = 0; k < HD / 4; ++k) {
        float4 t = reinterpret_cast<const float4*>(Whh)[k];
        wreg[4*k+0] = t.x; wreg[4*k+1] = t.y; wreg[4*k+2] = t.z; wreg[4*k+3] = t.w;
    }
    const float bias = (d == 0) ? (bih_f[tid] + bhh_f[tid]) : (bih_b[tid] + bhh_b[tid]);

    float h = h0[((size_t)d * BB + b) * HD + u];
    float c = c0[((size_t)d * BB + b) * HD + u];

    const int* srow = sent + (size_t)b * TT;
    const int tstep = (d == 0) ? 1 : -1;
    const int t0    = (d == 0) ? 0 : TT - 1;
    const int doff  = d * 256;
    const unsigned short* prj = (const unsigned short*)proj;

    // window-8 prefetch: cur holds xp (raw bf16 bits) for steps s0..s0+7
    uint32 cur[8], nxt[8];
    #pragma unroll
    for (int i = 0; i < 8; ++i)
        cur[i] = prj[(size_t)srow[t0 + i * tstep] * 512 + doff + tid];

    __hip_bfloat16* hp = Hbuf + ((size_t)t0 * BB + b) * 128 + d * 64 + u;
    const ptrdiff_t hstride = (ptrdiff_t)tstep * BB * 128;

    int pb = 0;
    for (int s0 = 0; s0 < TT; s0 += 8) {
        // burst-issue next window's 8 independent gathers
        #pragma unroll
        for (int i = 0; i < 8; ++i) {
            int sn = s0 + 8 + i;
            sn = (sn < TT) ? sn : TT - 1;              // clamped, values unused at tail
            nxt[i] = prj[(size_t)srow[t0 + sn * tstep] * 512 + doff + tid];
        }
        #pragma unroll
        for (int i = 0; i < 8; ++i) {
            const float xp = bf_lo(cur[i]);

            // g[tid] = bias + xp + sum_k h[k] * Whh[tid][k]
            float acc0 = bias + xp, acc1 = 0.f, acc2 = 0.f, acc3 = 0.f;
            #pragma unroll
            for (int k = 0; k < HD; k += 4) {
                float hk0 = rl_f(h, k + 0);
                float hk1 = rl_f(h, k + 1);
                float hk2 = rl_f(h, k + 2);
                float hk3 = rl_f(h, k + 3);
                acc0 = fmaf(hk0, wreg[k + 0], acc0);
                acc1 = fmaf(hk1, wreg[k + 1], acc1);
                acc2 = fmaf(hk2, wreg[k + 2], acc2);
                acc3 = fmaf(hk3, wreg[k + 3], acc3);
            }
            float g = (acc0 + acc1) + (acc2 + acc3);

            float a = (w == 2) ? tanh_f(g) : sigm_f(g);   // wave-uniform branch
            a_lds[pb][tid] = a;
            lds_barrier();
            float ai = a_lds[pb][u];
            float af = a_lds[pb][64 + u];
            float ag = a_lds[pb][128 + u];
            float ao = a_lds[pb][192 + u];
            c = af * c + ai * ag;
            h = ao * tanh_f(c);
            pb ^= 1;

            if (tid < 64)
                *hp = __float2bfloat16(h);
            hp += hstride;
        }
        #pragma unroll
        for (int i = 0; i < 8; ++i) cur[i] = nxt[i];
    }
}

// ---------- K3: emissions ----------
__global__ __launch_bounds__(128) void k3_emis(
    const __hip_bfloat16* __restrict__ Hbuf,
    const float* __restrict__ W_out, const float* __restrict__ b_out,
    float* __restrict__ emis)
{
    const int t = blockIdx.x;
    const int b = threadIdx.x;
    __shared__ float Wl[KK * 128];
    for (int i = threadIdx.x; i < KK * 128; i += 128) Wl[i] = W_out[i];
    __syncthreads();

    const __hip_bfloat16* hrow = Hbuf + ((size_t)t * BB + b) * 128;
    float acc[KK];
    #pragma unroll
    for (int k = 0; k < KK; ++k) acc[k] = b_out[k];

    #pragma unroll
    for (int u0 = 0; u0 < 128; u0 += 8) {
        uint4 hv = *reinterpret_cast<const uint4*>(hrow + u0);
        float hf[8];
        hf[0] = bf_lo(hv.x); hf[1] = bf_hi(hv.x);
        hf[2] = bf_lo(hv.y); hf[3] = bf_hi(hv.y);
        hf[4] = bf_lo(hv.z); hf[5] = bf_hi(hv.z);
        hf[6] = bf_lo(hv.w); hf[7] = bf_hi(hv.w);
        #pragma unroll
        for (int k = 0; k < KK; ++k) {
            #pragma unroll
            for (int r = 0; r < 8; ++r)
                acc[k] = fmaf(hf[r], Wl[k * 128 + u0 + r], acc[k]);
        }
    }
    float* e = emis + ((size_t)b * TT + t) * KK;
    #pragma unroll
    for (int k = 0; k < KK; k += 4) {
        float4 v = make_float4(acc[k], acc[k+1], acc[k+2], acc[k+3]);
        *reinterpret_cast<float4*>(e + k) = v;
    }
}

// ---------- K4: Viterbi per batch (1 wave). ----------
__global__ __launch_bounds__(64) void k4_viterbi(
    const float* __restrict__ emis, const float* __restrict__ trans,
    float* __restrict__ out)
{
    const int b    = blockIdx.x;
    const int lane = threadIdx.x;
    __shared__ float em_lds[TT * KK];                 // 24 KB
    __shared__ unsigned char bp[(TT - 1) * KK + 4];

    {
        const uint4* e4 = reinterpret_cast<const uint4*>(emis + (size_t)b * TT * KK);
        uint4* l4 = reinterpret_cast<uint4*>(em_lds);
        for (int i = lane; i < TT * KK / 4; i += 64) l4[i] = e4[i];
    }
    __syncthreads();

    const int jj = (lane < KK) ? lane : 0;
    float tc[KK];
    #pragma unroll
    for (int i = 0; i < KK; ++i) tc[i] = trans[i * KK + jj];   // column jj

    float vj = em_lds[jj];
    float sv[KK];
    #pragma unroll
    for (int i = 0; i < KK; ++i) sv[i] = rl_f(vj, i);

    for (int t = 1; t < TT; ++t) {
        float best = sv[0] + tc[0];
        int bi = 0;
        #pragma unroll
        for (int i = 1; i < KK; ++i) {
            float cnd = sv[i] + tc[i];
            bool gt = cnd > best;       // strict > keeps first max (jnp.argmax)
            best = gt ? cnd : best;
            bi   = gt ? i : bi;
        }
        if (lane < KK) bp[(t - 1) * KK + lane] = (unsigned char)bi;
        vj = best + em_lds[t * KK + jj];
        #pragma unroll
        for (int i = 0; i < KK; ++i) sv[i] = rl_f(vj, i);
    }

    float best = sv[0]; int bt = 0;
    #pragma unroll
    for (int i = 1; i < KK; ++i) { if (sv[i] > best) { best = sv[i]; bt = i; } }

    if (lane == 0) {
        out[b] = best;
        float* path = out + BB + (size_t)b * TT;
        int tag = bt;
        path[TT - 1] = (float)tag;
        for (int t = TT - 2; t >= 0; --t) {
            tag = bp[t * KK + tag];
            path[t] = (float)tag;
        }
    }
}

// ---------- launcher ----------
extern "C" void kernel_launch(void* const* d_in, const int* in_sizes, int n_in,
                              void* d_out, int out_size, void* d_ws, size_t ws_size,
                              hipStream_t stream) {
    const int*   sent  = (const int*)  d_in[0];
    const float* emb   = (const float*)d_in[1];
    const float* Wih_f = (const float*)d_in[2];
    const float* Whh_f = (const float*)d_in[3];
    const float* bih_f = (const float*)d_in[4];
    const float* bhh_f = (const float*)d_in[5];
    const float* Wih_b = (const float*)d_in[6];
    const float* Whh_b = (const float*)d_in[7];
    const float* bih_b = (const float*)d_in[8];
    const float* bhh_b = (const float*)d_in[9];
    const float* W_out = (const float*)d_in[10];
    const float* b_out = (const float*)d_in[11];
    const float* trans = (const float*)d_in[12];
    const float* h0    = (const float*)d_in[13];
    const float* c0    = (const float*)d_in[14];
    float* out = (float*)d_out;

    char* ws = (char*)d_ws;
    __hip_bfloat16* proj = (__hip_bfloat16*)ws;                       // V*512*2 B
    size_t off = (((size_t)VV * 512 * 2) + 255) & ~(size_t)255;
    __hip_bfloat16* Hbuf = (__hip_bfloat16*)(ws + off);               // T*B*128*2 B
    off += (((size_t)TT * BB * 128 * 2) + 255) & ~(size_t)255;
    float* emis = (float*)(ws + off);                                 // B*T*12*4 B

    k1_mfma<<<dim3((VV + 63) / 64), 256, 0, stream>>>(emb, Wih_f, Wih_b, proj);
    k2_lstm<<<dim3(2 * BB), 256, 0, stream>>>(sent, proj, Whh_f, Whh_b,
                                              bih_f, bhh_f, bih_b, bhh_b,
                                              h0, c0, Hbuf);
    k3_emis<<<dim3(TT), 128, 0, stream>>>(Hbuf, W_out, b_out, emis);
    k4_viterbi<<<dim3(BB), 64, 0, stream>>>(emis, trans, out);
}